// Round 12
// baseline (164.840 us; speedup 1.0000x reference)
//
#include <hip/hip_runtime.h>

static constexpr int N = 128;
static constexpr int F = 128;
static constexpr int H = 8;
static constexpr int NATTR = 3;
static constexpr int M = N * N;        // 16384
static constexpr int OUTW = 320;       // F + 8*16 + 8*8
static constexpr int MSL = 128;        // m-splits in edge attention
static constexpr int CH = M / MSL;     // 128 m per block
static constexpr float LOG2E = 1.4426950408889634f;

__device__ __forceinline__ float leaky(float x) { return fmaxf(x, 0.2f * x); }

// ---------------------------------------------------------------------------
// Prep: aself[3][8][N] = LOG2E * ((xsrc @ Wn) · aes). 24 blocks x 128 thr.
template <int K>
__global__ void __launch_bounds__(128)
k_prep(const float* __restrict__ xsrc, int xStride,
       const float* __restrict__ Wn,   // [3][8][F][K]
       const float* __restrict__ aes,  // [8][K]
       float* __restrict__ aself) {    // [3][8][N]
    int a = blockIdx.x / H, h = blockIdx.x % H;
    __shared__ float wv[F];
    int tid = threadIdx.x;             // 128 = F = N
    {
        const float* wp = Wn + ((size_t)(a * H + h) * F + tid) * K;
        const float* ap = aes + h * K;
        float acc = 0.f;
#pragma unroll
        for (int k = 0; k < K; ++k) acc += wp[k] * ap[k];
        wv[tid] = acc;
    }
    __syncthreads();
    const float4* xr4 = (const float4*)(xsrc + (size_t)a * xStride + (size_t)tid * F);
    float acc = 0.f;
#pragma unroll 4
    for (int f = 0; f < F / 4; ++f) {
        float4 v = xr4[f];
        acc += v.x * wv[f * 4 + 0] + v.y * wv[f * 4 + 1] +
               v.z * wv[f * 4 + 2] + v.w * wv[f * 4 + 3];
    }
    aself[(a * H + h) * N + tid] = acc * LOG2E;
}

// ---------------------------------------------------------------------------
// Edge-to-node attention, max arithmetic intensity: thread = (row, mg) owns
// ALL 24 (attr,head) combos for 16 m. adj read once; per-head v + moments
// staged in interleaved LDS tile sD[p][12] (p = o*8+mg). Moments partials.
// part record: [ms][n][ (a*8+h)*4 ] = float4(mom0, mom1, mom2, sum).
template <bool L1>
__global__ void __launch_bounds__(128)
k_ea(const float* __restrict__ E,      // [3][N][N]
     const float* __restrict__ aself,  // [3][8][N] (log2e-scaled)
     const float* __restrict__ We0,    // [8][3][4]
     const float* __restrict__ aen,    // [8][KE]
     const float* __restrict__ We1,    // [8][32][2] (L1 only)
     const float* __restrict__ adj,    // [N][M]
     float* __restrict__ part) {       // [MSL][N][96]
    __shared__ __align__(16) float sE[3 * CH];   // 1.5 KB
    __shared__ __align__(16) float sD[CH * 12];  // 6 KB
    __shared__ float sVa[24];

    int b = blockIdx.x;
    int ms = b & (MSL - 1);
    int nt = b >> 7;                   // 0..7
    int tid = threadIdx.x;             // 128 = 16 rows x 8 mg
    int mg = tid & 7, r = tid >> 3;
    int n = nt * 16 + r;
    int m0 = ms * CH;

    // stage E chunk (96 float4s by threads 0..95)
    if (tid < 96) {
        int pl = tid >> 5, c = tid & 31;
        *(float4*)&sE[pl * CH + c * 4] =
            *(const float4*)(E + (size_t)pl * M + m0 + c * 4);
    }
    // per-head edge-logit weights va[h][at] (threads 96..119)
    if (tid >= 96 && tid < 120) {
        int idx = tid - 96, h = idx / 3, at = idx % 3;
        float acc = 0.f;
        if (!L1) {
#pragma unroll
            for (int k = 0; k < 4; ++k)
                acc += We0[(h * 3 + at) * 4 + k] * aen[h * 4 + k];
        } else {
            for (int c = 0; c < 32; ++c) {
                float we0 = We0[((c >> 2) * 3 + at) * 4 + (c & 3)];
                acc += we0 * (We1[(h * 32 + c) * 2 + 0] * aen[h * 2 + 0] +
                              We1[(h * 32 + c) * 2 + 1] * aen[h * 2 + 1]);
            }
        }
        sVa[idx] = acc * LOG2E;
    }

    // per-thread a_self for the row (L2-hot, overlaps LDS staging)
    float u[3][8];
#pragma unroll
    for (int a = 0; a < 3; ++a)
#pragma unroll
        for (int h = 0; h < 8; ++h)
            u[a][h] = aself[(a * 8 + h) * N + n];
    // batch all adj loads for this thread's 16 m
    const float* adjp = adj + (size_t)n * M + m0 + mg * 16;
    float4 aq[4];
#pragma unroll
    for (int q = 0; q < 4; ++q) aq[q] = *(const float4*)(adjp + q * 4);
    __syncthreads();

    // build interleaved tile: thread p covers (o = p>>3, mgq = p&7)
    {
        int o = tid >> 3, mgq = tid & 7;
        int mm = mgq * 16 + o;
        float x0 = sE[mm], x1 = sE[CH + mm], x2 = sE[2 * CH + mm];
        float* d = &sD[tid * 12];
#pragma unroll
        for (int h = 0; h < 8; ++h)
            d[h] = sVa[h * 3 + 0] * x0 + sVa[h * 3 + 1] * x1 + sVa[h * 3 + 2] * x2;
        d[8] = x0; d[9] = x1; d[10] = x2; d[11] = 0.f;
    }
    __syncthreads();

    float mom[3][8][3];
    float sums[3][8];
#pragma unroll
    for (int a = 0; a < 3; ++a)
#pragma unroll
        for (int h = 0; h < 8; ++h) {
            sums[a][h] = 0.f;
            mom[a][h][0] = 0.f; mom[a][h][1] = 0.f; mom[a][h][2] = 0.f;
        }

#pragma unroll
    for (int o = 0; o < 16; ++o) {
        float av = (&aq[o >> 2].x)[o & 3] * LOG2E;
        const float* d = &sD[(o * 8 + mg) * 12];
        float x0 = d[8], x1 = d[9], x2 = d[10];
#pragma unroll
        for (int h = 0; h < 8; ++h) {
            float vh = d[h];
#pragma unroll
            for (int a = 0; a < 3; ++a) {
                float t = u[a][h] + vh;
                float p = __builtin_amdgcn_exp2f(fmaxf(t, 0.2f * t) + av);
                sums[a][h] += p;
                mom[a][h][0] += p * x0;
                mom[a][h][1] += p * x1;
                mom[a][h][2] += p * x2;
            }
        }
    }

    // butterfly-reduce over mg (lane bits 0-2)
#pragma unroll
    for (int off = 1; off < 8; off <<= 1) {
#pragma unroll
        for (int a = 0; a < 3; ++a)
#pragma unroll
            for (int h = 0; h < 8; ++h) {
                sums[a][h] += __shfl_xor(sums[a][h], off);
                mom[a][h][0] += __shfl_xor(mom[a][h][0], off);
                mom[a][h][1] += __shfl_xor(mom[a][h][1], off);
                mom[a][h][2] += __shfl_xor(mom[a][h][2], off);
            }
    }
    if (mg == 0) {
        float* pp = part + ((size_t)ms * N + n) * 96;
#pragma unroll
        for (int a = 0; a < 3; ++a)
#pragma unroll
            for (int h = 0; h < 8; ++h)
                *(float4*)&pp[(a * 8 + h) * 4] =
                    make_float4(mom[a][h][0], mom[a][h][1], mom[a][h][2], sums[a][h]);
    }
}

// ---------------------------------------------------------------------------
// Mid: block = (a, h, ntile of 32 rows) = 96 blocks. Reduces moments, applies
// W-fixup -> nf_e, feat from LDS-staged X rows, feat2, s2/n2.
template <int K, int KE, bool FIRST>
__global__ void __launch_bounds__(256)
k_mid(const float* __restrict__ xsrc,    // X (stride 0) | xh
      int xStride,
      const float* __restrict__ Wn,      // [3][8][F][K]
      const float* __restrict__ part,    // [MSL][N][96]
      const float* __restrict__ We0,     // [8][3][4]
      const float* __restrict__ We1,     // [8][32][2] (KE==2 only)
      const float* __restrict__ be,      // [8][KE]
      const float* __restrict__ Wct,     // [8][K+KE][K]
      const float* __restrict__ bct,     // [8][K]
      const float* __restrict__ ans,     // [3][8][K]
      const float* __restrict__ ann,     // [3][8][K]
      const float* __restrict__ X,       // FIRST copy src
      float* __restrict__ out,
      float* __restrict__ feat2,         // [3][8][N][16]
      float* __restrict__ s2,            // [3][8][N]
      float* __restrict__ n2) {          // [3][8][N]
    constexpr int CIN = K + KE;
    constexpr int XP = 132;              // padded row stride
    __shared__ __align__(16) float sWn[F * K];
    __shared__ __align__(16) float sW[CIN * K];
    __shared__ __align__(16) float sIn[32 * CIN];
    __shared__ __align__(16) float sF2[32 * K];
    __shared__ __align__(16) float sX[32 * XP];

    int b = blockIdx.x;
    int nt = b & 3, h = (b >> 2) & 7, a = b >> 5;
    int n0 = nt * 32;
    int tid = threadIdx.x;

    for (int i = tid; i < F * K; i += 256)
        sWn[i] = Wn[(size_t)(a * H + h) * F * K + i];
    for (int i = tid; i < CIN * K; i += 256) sW[i] = Wct[h * CIN * K + i];
    for (int i = tid; i < 32 * 32; i += 256) {
        int r = i >> 5, c = i & 31;
        float4 v = *(const float4*)(xsrc + (size_t)a * xStride +
                                    (size_t)(n0 + r) * F + c * 4);
        sX[r * XP + c * 4 + 0] = v.x;
        sX[r * XP + c * 4 + 1] = v.y;
        sX[r * XP + c * 4 + 2] = v.z;
        sX[r * XP + c * 4 + 3] = v.w;
    }

    // ---- moment reduce: 32 rows x 8 groups over MSL splits ----
    {
        int r = tid >> 3, g = tid & 7;
        int n = n0 + r;
        float m0 = 0.f, m1 = 0.f, m2 = 0.f, sv = 0.f;
        for (int ms = g; ms < MSL; ms += 8) {
            const float4 v = *(const float4*)(
                part + ((size_t)ms * N + n) * 96 + (a * 8 + h) * 4);
            m0 += v.x; m1 += v.y; m2 += v.z; sv += v.w;
        }
#pragma unroll
        for (int off = 1; off < 8; off <<= 1) {
            m0 += __shfl_xor(m0, off);
            m1 += __shfl_xor(m1, off);
            m2 += __shfl_xor(m2, off);
            sv += __shfl_xor(sv, off);
        }
        if (g == 0) {
            float inv = 1.f / sv;
            float mom[3] = {m0, m1, m2};
            if (KE == 4) {
#pragma unroll
                for (int k = 0; k < 4; ++k) {
                    float acc = 0.f;
#pragma unroll
                    for (int at = 0; at < 3; ++at)
                        acc += We0[(h * 3 + at) * 4 + k] * mom[at];
                    sIn[r * CIN + K + k] = acc * inv + be[h * 4 + k];
                }
            } else {
                float wc[3][2];
#pragma unroll
                for (int at = 0; at < 3; ++at) {
                    float w0 = 0.f, w1 = 0.f;
                    for (int c = 0; c < 32; ++c) {
                        float we0 = We0[((c >> 2) * 3 + at) * 4 + (c & 3)];
                        w0 += we0 * We1[(h * 32 + c) * 2 + 0];
                        w1 += we0 * We1[(h * 32 + c) * 2 + 1];
                    }
                    wc[at][0] = w0; wc[at][1] = w1;
                }
#pragma unroll
                for (int k = 0; k < 2; ++k) {
                    float acc = wc[0][k] * mom[0] + wc[1][k] * mom[1] +
                                wc[2][k] * mom[2];
                    sIn[r * CIN + K + k] = acc * inv + be[h * 2 + k];
                }
            }
        }
    }
    if (FIRST && h == 0) {
        for (int i = tid; i < 32 * F; i += 256) {
            int n = n0 + (i >> 7);
            int f = i & (F - 1);
            out[(n * NATTR + a) * OUTW + f] = X[n * F + f];
        }
    }
    __syncthreads();

    // ---- feat for the 32 rows (from LDS) ----
    for (int o = tid; o < 32 * K; o += 256) {
        int r = o / K, k = o % K;
        const float* xr = &sX[r * XP];
        float acc = 0.f;
#pragma unroll 4
        for (int f = 0; f < F; ++f) acc += xr[f] * sWn[f * K + k];
        sIn[r * CIN + k] = acc;
    }
    __syncthreads();

    // ---- feat2 + s2/n2 ----
    for (int o = tid; o < 32 * K; o += 256) {
        int r = o / K, k = o % K;
        float acc = bct[h * K + k];
        for (int c = 0; c < CIN; ++c) acc += sIn[r * CIN + c] * sW[c * K + k];
        sF2[o] = acc;
        feat2[((size_t)(a * H + h) * N + n0 + r) * 16 + k] = acc;
    }
    __syncthreads();
    if (tid < 32) {
        int r = tid;
        float ss = 0.f, nn = 0.f;
        for (int k = 0; k < K; ++k) {
            ss += sF2[r * K + k] * ans[(a * H + h) * K + k];
            nn += sF2[r * K + k] * ann[(a * H + h) * K + k];
        }
        s2[(a * H + h) * N + n0 + r] = ss;
        n2[(a * H + h) * N + n0 + r] = nn;
    }
}

// ---------------------------------------------------------------------------
// Node: block = (a, h, itile of 16 rows) = 192 blocks.
template <int K, bool FIRST>
__global__ void __launch_bounds__(256)
k_node(const float* __restrict__ feat2,   // [3][8][N][16]
       const float* __restrict__ s2,      // [3][8][N]
       const float* __restrict__ n2,      // [3][8][N]
       const float* __restrict__ Einfo,   // [3][N][N]
       const float* __restrict__ Amat,    // [3][N][N]
       const float* __restrict__ bn,      // [3][8][K]
       float* __restrict__ out, int outOff,
       float* __restrict__ xh_out,        // [3][N][128] or nullptr
       float* __restrict__ einfo_out) {   // [3][N][N] or nullptr
    __shared__ __align__(16) float sF2[N * K];
    __shared__ __align__(16) float sS2[N];
    __shared__ __align__(16) float sn2[N];
    __shared__ __align__(16) float sdE[N];
    __shared__ __align__(16) float scE[N];
    __shared__ __align__(16) float sAlpha[4 * N];
    __shared__ __align__(16) float sRed[256];

    int b = blockIdx.x;
    int itile = b & 7, h = (b >> 3) & 7, a = b >> 6;
    int tid = threadIdx.x;

    for (int i = tid; i < N * K; i += 256)
        sF2[i] = feat2[((size_t)(a * H + h) * N + i / K) * 16 + i % K];
    if (tid < N) {
        sS2[tid] = s2[(a * H + h) * N + tid];
        sn2[tid] = n2[(a * H + h) * N + tid];
    }
    __syncthreads();

    {
        int m = tid & 127, w = tid >> 7;
        const float* Ep = Einfo + (size_t)a * M;
        float dacc = 0.f, cacc = 0.f;
        for (int j = w * 64; j < w * 64 + 64; ++j) {
            float v = Ep[j * N + m];
            dacc += sn2[j] * v;
            cacc += v;
        }
        sRed[tid] = dacc;
        sAlpha[w * N + m] = cacc;
        __syncthreads();
        if (tid < N) {
            sdE[tid] = sRed[tid] + sRed[128 + tid];
            scE[tid] = sAlpha[tid] + sAlpha[N + tid];
        }
    }
    __syncthreads();

    for (int pass = 0; pass < 4; ++pass) {
        int r = tid >> 6;
        int lane = tid & 63;
        int i = itile * 16 + pass * 4 + r;
        float s = sS2[i];
        const float* Ap = Amat + ((size_t)a * N + i) * N;
        float v0 = leaky(s * scE[lane] + sdE[lane]) + Ap[lane];
        float v1 = leaky(s * scE[lane + 64] + sdE[lane + 64]) + Ap[lane + 64];
        float p0 = __expf(v0), p1 = __expf(v1);
        float ssum = p0 + p1;
#pragma unroll
        for (int off = 1; off < 64; off <<= 1) ssum += __shfl_xor(ssum, off);
        float inv = 1.f / ssum;
        float a0 = p0 * inv, a1 = p1 * inv;
        sAlpha[r * N + lane] = a0;
        sAlpha[r * N + lane + 64] = a1;
        if (FIRST && h == H - 1) {
            einfo_out[((size_t)a * N + i) * N + lane] = a0;
            einfo_out[((size_t)a * N + i) * N + lane + 64] = a1;
        }
        __syncthreads();
        {
            int rr = tid >> 6, g = (tid >> 4) & 3, k = tid & 15;
            float acc = 0.f;
            if (k < K) {
                for (int it = 0; it < 32; ++it) {
                    int mm = g + 4 * it;
                    acc += sAlpha[rr * N + mm] * sF2[mm * K + k];
                }
            }
            sRed[tid] = acc;
        }
        __syncthreads();
        {
            int rr = tid >> 6, k = tid & 63;
            if (k < K) {
                float tot = bn[(a * H + h) * K + k];
#pragma unroll
                for (int g = 0; g < 4; ++g) tot += sRed[rr * 64 + g * 16 + k];
                float e = tot > 0.f ? tot : __expf(tot) - 1.f;   // elu
                int i2 = itile * 16 + pass * 4 + rr;
                out[(i2 * NATTR + a) * OUTW + outOff + h * K + k] = e;
                if (FIRST)
                    xh_out[((size_t)a * N + i2) * F + h * K + k] = e;
            }
        }
        __syncthreads();
    }
}

// ---------------------------------------------------------------------------
extern "C" void kernel_launch(void* const* d_in, const int* in_sizes, int n_in,
                              void* d_out, int out_size, void* d_ws, size_t ws_size,
                              hipStream_t stream) {
    const float* X    = (const float*)d_in[0];
    const float* A    = (const float*)d_in[1];
    const float* E    = (const float*)d_in[2];
    const float* adj  = (const float*)d_in[3];
    const float* Wn0  = (const float*)d_in[4];
    const float* bn0  = (const float*)d_in[5];
    const float* an0s = (const float*)d_in[6];
    const float* an0n = (const float*)d_in[7];
    const float* Wn1  = (const float*)d_in[8];
    const float* bn1  = (const float*)d_in[9];
    const float* an1s = (const float*)d_in[10];
    const float* an1n = (const float*)d_in[11];
    const float* We0  = (const float*)d_in[12];
    const float* be0  = (const float*)d_in[13];
    const float* We1  = (const float*)d_in[14];
    const float* be1  = (const float*)d_in[15];
    const float* Wct0 = (const float*)d_in[16];
    const float* bct0 = (const float*)d_in[17];
    const float* Wct1 = (const float*)d_in[18];
    const float* bct1 = (const float*)d_in[19];
    const float* ae0s = (const float*)d_in[20];
    const float* ae0n = (const float*)d_in[21];
    const float* ae1s = (const float*)d_in[22];
    const float* ae1n = (const float*)d_in[23];
    float* out = (float*)d_out;

    float* p = (float*)d_ws;
    float* part  = p; p += (size_t)MSL * N * 96;
    float* aself = p; p += NATTR * H * N;
    float* feat2 = p; p += NATTR * H * N * 16;
    float* s2b   = p; p += NATTR * H * N;
    float* n2b   = p; p += NATTR * H * N;
    float* einfo = p; p += NATTR * N * N;
    float* xh    = p; p += NATTR * N * F;

    // ---- layer 0 ----
    k_prep<16><<<dim3(24), dim3(128), 0, stream>>>(X, 0, Wn0, ae0s, aself);
    k_ea<false><<<dim3(8 * MSL), dim3(128), 0, stream>>>(
        E, aself, We0, ae0n, nullptr, adj, part);
    k_mid<16, 4, true><<<dim3(96), dim3(256), 0, stream>>>(
        X, 0, Wn0, part, We0, nullptr, be0, Wct0, bct0, an0s, an0n, X, out,
        feat2, s2b, n2b);
    k_node<16, true><<<dim3(192), dim3(256), 0, stream>>>(
        feat2, s2b, n2b, E, A, bn0, out, F, xh, einfo);

    // ---- layer 1 ----
    k_prep<8><<<dim3(24), dim3(128), 0, stream>>>(xh, N * F, Wn1, ae1s, aself);
    k_ea<true><<<dim3(8 * MSL), dim3(128), 0, stream>>>(
        E, aself, We0, ae1n, We1, adj, part);
    k_mid<8, 2, false><<<dim3(96), dim3(256), 0, stream>>>(
        xh, N * F, Wn1, part, We0, We1, be1, Wct1, bct1, an1s, an1n,
        nullptr, nullptr, feat2, s2b, n2b);
    k_node<8, false><<<dim3(192), dim3(256), 0, stream>>>(
        feat2, s2b, n2b, einfo, A, bn1, out, F + 128, nullptr, nullptr);
}

// Round 13
// 90.874 us; speedup vs baseline: 1.8139x; 1.8139x over previous
//
#include <hip/hip_runtime.h>

static constexpr int N = 128;
static constexpr int F = 128;
static constexpr int H = 8;
static constexpr int NATTR = 3;
static constexpr int M = N * N;        // 16384
static constexpr int OUTW = 320;       // F + 8*16 + 8*8
static constexpr int MSL = 32;         // m-splits in edge attention
static constexpr int CH = M / MSL;     // 512
static constexpr float LOG2E = 1.4426950408889634f;

__device__ __forceinline__ float leaky(float x) { return fmaxf(x, 0.2f * x); }

// ---------------------------------------------------------------------------
// expA[n][m] = exp2(log2e * adj[n][m]); computed once, used by both layers.
__global__ void __launch_bounds__(256)
k_expadj(const float* __restrict__ adj, float* __restrict__ expA) {
    int i = (blockIdx.x * 256 + threadIdx.x) * 4;
    float4 v = *(const float4*)(adj + i);
    float4 r;
    r.x = __builtin_amdgcn_exp2f(v.x * LOG2E);
    r.y = __builtin_amdgcn_exp2f(v.y * LOG2E);
    r.z = __builtin_amdgcn_exp2f(v.z * LOG2E);
    r.w = __builtin_amdgcn_exp2f(v.w * LOG2E);
    *(float4*)(expA + i) = r;
}

// ---------------------------------------------------------------------------
// Edge-to-node attention, R7 structure + exp-free hot loop. Block =
// (head-quad, n-tile 16, m-chunk 512), all 3 attrs x 4 heads. fe + exp-tables
// T1/T2 staged in LDS; a_self inline via wvec; branch-select instead of exp.
template <int KE, bool L1>
__global__ void __launch_bounds__(256)
k_ea(const float* __restrict__ E,      // [3][N][N]
     const float* __restrict__ xsrc,   // X (stride 0) | xh [3][N][128]
     int xStride,
     const float* __restrict__ Wn,     // [3][8][F][KW]
     const float* __restrict__ aes,    // [8][KW]
     const float* __restrict__ We0,    // [8][3][4]
     const float* __restrict__ aen,    // [8][KE]
     const float* __restrict__ We1,    // [8][32][2] (L1 only)
     const float* __restrict__ expA,   // [N][M]  (= exp2(log2e*adj))
     float* __restrict__ part) {       // [3][8][N][MSL][8]
    constexpr int KW = L1 ? 8 : 16;
    __shared__ __align__(16) float sFe[4 * CH * KE];
    __shared__ __align__(16) float sT1[4 * CH];
    __shared__ __align__(16) float sT2[4 * CH];
    __shared__ __align__(16) float sWv[12 * 128];
    __shared__ __align__(16) float sWc[48];

    int b = blockIdx.x;
    int ms = b & (MSL - 1);
    int nt = (b >> 5) & 7;
    int h0 = (b >> 8) * 4;
    int tid = threadIdx.x;
    int r = tid >> 4, l = tid & 15;
    int n = nt * 16 + r;
    int m0 = ms * CH;

    // ---- stage wvec[c][f] = log2e * sum_k Wn[a][h][f][k]*aes[h][k] ----
    for (int idx = tid; idx < 12 * 128; idx += 256) {
        int c = idx >> 7, f = idx & 127;
        int a = c >> 2, h = h0 + (c & 3);
        const float* wp = Wn + ((size_t)(a * H + h) * F + f) * KW;
        const float* ap = aes + h * KW;
        float acc = 0.f;
#pragma unroll
        for (int k = 0; k < KW; ++k) acc += wp[k] * ap[k];
        sWv[idx] = acc * LOG2E;
    }
    if (L1) {
        if (tid < 24) {
            int hh = tid / 6, rem = tid % 6, at = rem >> 1, k2 = rem & 1;
            int h = h0 + hh;
            float acc = 0.f;
            for (int c = 0; c < 32; ++c)
                acc += We0[((c >> 2) * 3 + at) * 4 + (c & 3)] *
                       We1[(h * 32 + c) * 2 + k2];
            sWc[(hh * 3 + at) * 2 + k2] = acc;
        }
        __syncthreads();
    }
    // ---- stage fe + exp tables for the chunk: [4h][512] ----
    for (int idx = tid; idx < 4 * CH; idx += 256) {
        int hh = idx >> 9, mm = idx & (CH - 1);
        int m = m0 + mm, h = h0 + hh;
        float e0 = E[m], e1 = E[M + m], e2 = E[2 * M + m];
        float aa;
        if (!L1) {
            aa = 0.f;
#pragma unroll
            for (int k = 0; k < 4; ++k) {
                float f = e0 * We0[(h * 3 + 0) * 4 + k] +
                          e1 * We0[(h * 3 + 1) * 4 + k] +
                          e2 * We0[(h * 3 + 2) * 4 + k];
                sFe[(hh * CH + mm) * 4 + k] = f;
                aa += f * aen[h * 4 + k];
            }
        } else {
            float f0 = e0 * sWc[(hh * 3 + 0) * 2 + 0] + e1 * sWc[(hh * 3 + 1) * 2 + 0] +
                       e2 * sWc[(hh * 3 + 2) * 2 + 0];
            float f1 = e0 * sWc[(hh * 3 + 0) * 2 + 1] + e1 * sWc[(hh * 3 + 1) * 2 + 1] +
                       e2 * sWc[(hh * 3 + 2) * 2 + 1];
            sFe[(hh * CH + mm) * 2 + 0] = f0;
            sFe[(hh * CH + mm) * 2 + 1] = f1;
            aa = f0 * aen[h * 2 + 0] + f1 * aen[h * 2 + 1];
        }
        float sv = aa * LOG2E;                 // scaled v
        sT1[hh * CH + mm] = __builtin_amdgcn_exp2f(sv);
        sT2[hh * CH + mm] = __builtin_amdgcn_exp2f(0.2f * sv);
    }
    __syncthreads();

    // ---- a_self inline -> EU1/EU2/RU1 per (a, hh) ----
    float EU1[NATTR][4], EU2[NATTR][4], RU1[NATTR][4];
#pragma unroll
    for (int a = 0; a < NATTR; ++a) {
        const float* xr = xsrc + (size_t)a * xStride + (size_t)n * F;
        float xv[8];
#pragma unroll
        for (int j = 0; j < 8; ++j) xv[j] = xr[l + 16 * j];
#pragma unroll
        for (int hh = 0; hh < 4; ++hh) {
            const float* wr = sWv + (a * 4 + hh) * 128;
            float d = 0.f;
#pragma unroll
            for (int j = 0; j < 8; ++j) d += xv[j] * wr[l + 16 * j];
#pragma unroll
            for (int off = 1; off < 16; off <<= 1) d += __shfl_xor(d, off);
            EU1[a][hh] = __builtin_amdgcn_exp2f(d);        // exp2(u)
            EU2[a][hh] = __builtin_amdgcn_exp2f(0.2f * d); // exp2(0.2u)
            RU1[a][hh] = __builtin_amdgcn_exp2f(-d);       // exp2(-u): T1>=RU1 <=> u+v>=0
        }
    }

    // ---- main loop over the 512-m chunk (exp-free) ----
    float sum[4][NATTR];
    float acc[4][NATTR][KE];
#pragma unroll
    for (int hh = 0; hh < 4; ++hh)
#pragma unroll
        for (int a = 0; a < NATTR; ++a) {
            sum[hh][a] = 0.f;
#pragma unroll
            for (int k = 0; k < KE; ++k) acc[hh][a][k] = 0.f;
        }

    const float* eAp = expA + (size_t)n * M + m0;
    for (int i = l * 4; i < CH; i += 64) {
        const float4 eq = *(const float4*)(eAp + i);
        float4 t1v[4], t2v[4];
#pragma unroll
        for (int hh = 0; hh < 4; ++hh) {
            t1v[hh] = *(const float4*)&sT1[hh * CH + i];
            t2v[hh] = *(const float4*)&sT2[hh * CH + i];
        }
#pragma unroll
        for (int j = 0; j < 4; ++j) {
            float eAj = (&eq.x)[j];
#pragma unroll
            for (int hh = 0; hh < 4; ++hh) {
                float T1 = (&t1v[hh].x)[j];
                float T2 = (&t2v[hh].x)[j];
                float fv[KE];
                if (KE == 4) {
                    const float4 fq = *(const float4*)&sFe[(hh * CH + i + j) * 4];
                    fv[0] = fq.x; fv[1] = fq.y; fv[2] = fq.z; fv[3] = fq.w;
                } else {
                    const float2 fq = *(const float2*)&sFe[(hh * CH + i + j) * 2];
                    fv[0] = fq.x; fv[1] = fq.y;
                }
                float tA1 = T1 * eAj;
                float tA2 = T2 * eAj;
#pragma unroll
                for (int a = 0; a < NATTR; ++a) {
                    float b1 = EU1[a][hh] * tA1;
                    float b2 = EU2[a][hh] * tA2;
                    float p = (T1 >= RU1[a][hh]) ? b1 : b2;
                    sum[hh][a] += p;
#pragma unroll
                    for (int k = 0; k < KE; ++k) acc[hh][a][k] += p * fv[k];
                }
            }
        }
    }

    // ---- butterfly-reduce within each 16-lane row group, write partials ----
#pragma unroll
    for (int off = 1; off < 16; off <<= 1) {
#pragma unroll
        for (int hh = 0; hh < 4; ++hh)
#pragma unroll
            for (int a = 0; a < NATTR; ++a) {
                sum[hh][a] += __shfl_xor(sum[hh][a], off);
#pragma unroll
                for (int k = 0; k < KE; ++k) acc[hh][a][k] += __shfl_xor(acc[hh][a][k], off);
            }
    }
    if (l == 0) {
#pragma unroll
        for (int hh = 0; hh < 4; ++hh)
#pragma unroll
            for (int a = 0; a < NATTR; ++a) {
                float* pp = part + (((size_t)(a * H + h0 + hh) * N + n) * MSL + ms) * 8;
#pragma unroll
                for (int k = 0; k < KE; ++k) pp[k] = acc[hh][a][k];
                pp[7] = sum[hh][a];
            }
    }
}

// ---------------------------------------------------------------------------
// Mid: block = (a, h, ntile of 32 rows) = 96 blocks. Reduces part ONCE,
// inline feat for its 32 rows, feat2 = [feat|nf_e]@Wct + bct, s2/n2.
template <int K, int KE, bool FIRST>
__global__ void __launch_bounds__(256)
k_mid(const float* __restrict__ xsrc,    // X (stride 0) | xh
      int xStride,
      const float* __restrict__ Wn,      // [3][8][F][K]
      const float* __restrict__ part,    // [3][8][N][MSL][8]
      const float* __restrict__ be,      // [8][KE]
      const float* __restrict__ Wct,     // [8][K+KE][K]
      const float* __restrict__ bct,     // [8][K]
      const float* __restrict__ ans,     // [3][8][K]
      const float* __restrict__ ann,     // [3][8][K]
      const float* __restrict__ X,       // FIRST copy src
      float* __restrict__ out,
      float* __restrict__ feat2,         // [3][8][N][16]
      float* __restrict__ s2,            // [3][8][N]
      float* __restrict__ n2) {          // [3][8][N]
    constexpr int CIN = K + KE;
    __shared__ __align__(16) float sWn[F * K];
    __shared__ __align__(16) float sW[CIN * K];
    __shared__ __align__(16) float sIn[32 * CIN];
    __shared__ __align__(16) float sF2[32 * K];

    int b = blockIdx.x;
    int nt = b & 3, h = (b >> 2) & 7, a = b >> 5;
    int n0 = nt * 32;
    int tid = threadIdx.x;

    for (int i = tid; i < F * K; i += 256)
        sWn[i] = Wn[(size_t)(a * H + h) * F * K + i];
    for (int i = tid; i < CIN * K; i += 256) sW[i] = Wct[h * CIN * K + i];

    // ---- part reduce: 32 rows x 8 groups ----
    {
        int r = tid >> 3, g = tid & 7;
        int n = n0 + r;
        const float* pp = part + ((size_t)(a * H + h) * N + n) * MSL * 8;
        float av[4] = {0.f, 0.f, 0.f, 0.f};
        float sv = 0.f;
        for (int ms = g; ms < MSL; ms += 8) {
            const float4 x = *(const float4*)(pp + ms * 8);
            const float4 y = *(const float4*)(pp + ms * 8 + 4);
            av[0] += x.x; av[1] += x.y;
            if (KE == 4) { av[2] += x.z; av[3] += x.w; }
            sv += y.w;
        }
#pragma unroll
        for (int off = 1; off < 8; off <<= 1) {
#pragma unroll
            for (int k = 0; k < KE; ++k) av[k] += __shfl_xor(av[k], off);
            sv += __shfl_xor(sv, off);
        }
        if (g == 0) {
            float inv = 1.f / sv;
#pragma unroll
            for (int k = 0; k < KE; ++k)
                sIn[r * CIN + K + k] = av[k] * inv + be[h * KE + k];
        }
    }
    if (FIRST && h == 0) {
        for (int i = tid; i < 32 * F; i += 256) {
            int n = n0 + (i >> 7);
            int f = i & (F - 1);
            out[(n * NATTR + a) * OUTW + f] = X[n * F + f];
        }
    }
    __syncthreads();

    // ---- inline feat for the 32 rows ----
    for (int o = tid; o < 32 * K; o += 256) {
        int r = o / K, k = o % K;
        const float* xr = xsrc + (size_t)a * xStride + (size_t)(n0 + r) * F;
        float acc = 0.f;
        for (int f = 0; f < F; ++f) acc += xr[f] * sWn[f * K + k];
        sIn[r * CIN + k] = acc;
    }
    __syncthreads();

    // ---- feat2 + s2/n2 ----
    for (int o = tid; o < 32 * K; o += 256) {
        int r = o / K, k = o % K;
        float acc = bct[h * K + k];
        for (int c = 0; c < CIN; ++c) acc += sIn[r * CIN + c] * sW[c * K + k];
        sF2[o] = acc;
        feat2[((size_t)(a * H + h) * N + n0 + r) * 16 + k] = acc;
    }
    __syncthreads();
    if (tid < 32) {
        int r = tid;
        float ss = 0.f, nn = 0.f;
        for (int k = 0; k < K; ++k) {
            ss += sF2[r * K + k] * ans[(a * H + h) * K + k];
            nn += sF2[r * K + k] * ann[(a * H + h) * K + k];
        }
        s2[(a * H + h) * N + n0 + r] = ss;
        n2[(a * H + h) * N + n0 + r] = nn;
    }
}

// ---------------------------------------------------------------------------
// Node: block = (a, h, itile of 16 rows) = 192 blocks.
template <int K, bool FIRST>
__global__ void __launch_bounds__(256)
k_node(const float* __restrict__ feat2,   // [3][8][N][16]
       const float* __restrict__ s2,      // [3][8][N]
       const float* __restrict__ n2,      // [3][8][N]
       const float* __restrict__ Einfo,   // [3][N][N]
       const float* __restrict__ Amat,    // [3][N][N]
       const float* __restrict__ bn,      // [3][8][K]
       float* __restrict__ out, int outOff,
       float* __restrict__ xh_out,        // [3][N][128] or nullptr
       float* __restrict__ einfo_out) {   // [3][N][N] or nullptr
    __shared__ __align__(16) float sF2[N * K];
    __shared__ __align__(16) float sS2[N];
    __shared__ __align__(16) float sn2[N];
    __shared__ __align__(16) float sdE[N];
    __shared__ __align__(16) float scE[N];
    __shared__ __align__(16) float sAlpha[4 * N];
    __shared__ __align__(16) float sRed[256];

    int b = blockIdx.x;
    int itile = b & 7, h = (b >> 3) & 7, a = b >> 6;
    int tid = threadIdx.x;

    for (int i = tid; i < N * K; i += 256)
        sF2[i] = feat2[((size_t)(a * H + h) * N + i / K) * 16 + i % K];
    if (tid < N) {
        sS2[tid] = s2[(a * H + h) * N + tid];
        sn2[tid] = n2[(a * H + h) * N + tid];
    }
    __syncthreads();

    {
        int m = tid & 127, w = tid >> 7;
        const float* Ep = Einfo + (size_t)a * M;
        float dacc = 0.f, cacc = 0.f;
        for (int j = w * 64; j < w * 64 + 64; ++j) {
            float v = Ep[j * N + m];
            dacc += sn2[j] * v;
            cacc += v;
        }
        sRed[tid] = dacc;
        sAlpha[w * N + m] = cacc;
        __syncthreads();
        if (tid < N) {
            sdE[tid] = sRed[tid] + sRed[128 + tid];
            scE[tid] = sAlpha[tid] + sAlpha[N + tid];
        }
    }
    __syncthreads();

    for (int pass = 0; pass < 4; ++pass) {
        int r = tid >> 6;
        int lane = tid & 63;
        int i = itile * 16 + pass * 4 + r;
        float s = sS2[i];
        const float* Ap = Amat + ((size_t)a * N + i) * N;
        float v0 = leaky(s * scE[lane] + sdE[lane]) + Ap[lane];
        float v1 = leaky(s * scE[lane + 64] + sdE[lane + 64]) + Ap[lane + 64];
        float p0 = __expf(v0), p1 = __expf(v1);
        float ssum = p0 + p1;
#pragma unroll
        for (int off = 1; off < 64; off <<= 1) ssum += __shfl_xor(ssum, off);
        float inv = 1.f / ssum;
        float a0 = p0 * inv, a1 = p1 * inv;
        sAlpha[r * N + lane] = a0;
        sAlpha[r * N + lane + 64] = a1;
        if (FIRST && h == H - 1) {
            einfo_out[((size_t)a * N + i) * N + lane] = a0;
            einfo_out[((size_t)a * N + i) * N + lane + 64] = a1;
        }
        __syncthreads();
        {
            int rr = tid >> 6, g = (tid >> 4) & 3, k = tid & 15;
            float acc = 0.f;
            if (k < K) {
                for (int it = 0; it < 32; ++it) {
                    int mm = g + 4 * it;
                    acc += sAlpha[rr * N + mm] * sF2[mm * K + k];
                }
            }
            sRed[tid] = acc;
        }
        __syncthreads();
        {
            int rr = tid >> 6, k = tid & 63;
            if (k < K) {
                float tot = bn[(a * H + h) * K + k];
#pragma unroll
                for (int g = 0; g < 4; ++g) tot += sRed[rr * 64 + g * 16 + k];
                float e = tot > 0.f ? tot : __expf(tot) - 1.f;   // elu
                int i2 = itile * 16 + pass * 4 + rr;
                out[(i2 * NATTR + a) * OUTW + outOff + h * K + k] = e;
                if (FIRST)
                    xh_out[((size_t)a * N + i2) * F + h * K + k] = e;
            }
        }
        __syncthreads();
    }
}

// ---------------------------------------------------------------------------
extern "C" void kernel_launch(void* const* d_in, const int* in_sizes, int n_in,
                              void* d_out, int out_size, void* d_ws, size_t ws_size,
                              hipStream_t stream) {
    const float* X    = (const float*)d_in[0];
    const float* A    = (const float*)d_in[1];
    const float* E    = (const float*)d_in[2];
    const float* adj  = (const float*)d_in[3];
    const float* Wn0  = (const float*)d_in[4];
    const float* bn0  = (const float*)d_in[5];
    const float* an0s = (const float*)d_in[6];
    const float* an0n = (const float*)d_in[7];
    const float* Wn1  = (const float*)d_in[8];
    const float* bn1  = (const float*)d_in[9];
    const float* an1s = (const float*)d_in[10];
    const float* an1n = (const float*)d_in[11];
    const float* We0  = (const float*)d_in[12];
    const float* be0  = (const float*)d_in[13];
    const float* We1  = (const float*)d_in[14];
    const float* be1  = (const float*)d_in[15];
    const float* Wct0 = (const float*)d_in[16];
    const float* bct0 = (const float*)d_in[17];
    const float* Wct1 = (const float*)d_in[18];
    const float* bct1 = (const float*)d_in[19];
    const float* ae0s = (const float*)d_in[20];
    const float* ae0n = (const float*)d_in[21];
    const float* ae1s = (const float*)d_in[22];
    const float* ae1n = (const float*)d_in[23];
    float* out = (float*)d_out;

    float* p = (float*)d_ws;
    float* expA  = p; p += (size_t)N * M;
    float* part  = p; p += (size_t)NATTR * H * N * MSL * 8;
    float* feat2 = p; p += NATTR * H * N * 16;
    float* s2b   = p; p += NATTR * H * N;
    float* n2b   = p; p += NATTR * H * N;
    float* einfo = p; p += NATTR * N * N;
    float* xh    = p; p += NATTR * N * F;

    // adj -> exp2 table (once; adj is layer-invariant)
    k_expadj<<<dim3(N * M / 1024), dim3(256), 0, stream>>>(adj, expA);

    // ---- layer 0 ----
    k_ea<4, false><<<dim3(512), dim3(256), 0, stream>>>(
        E, X, 0, Wn0, ae0s, We0, ae0n, nullptr, expA, part);
    k_mid<16, 4, true><<<dim3(96), dim3(256), 0, stream>>>(
        X, 0, Wn0, part, be0, Wct0, bct0, an0s, an0n, X, out,
        feat2, s2b, n2b);
    k_node<16, true><<<dim3(192), dim3(256), 0, stream>>>(
        feat2, s2b, n2b, E, A, bn0, out, F, xh, einfo);

    // ---- layer 1 ----
    k_ea<2, true><<<dim3(512), dim3(256), 0, stream>>>(
        E, xh, N * F, Wn1, ae1s, We0, ae1n, We1, expA, part);
    k_mid<8, 2, false><<<dim3(96), dim3(256), 0, stream>>>(
        xh, N * F, Wn1, part, be1, Wct1, bct1, an1s, an1n, nullptr, nullptr,
        feat2, s2b, n2b);
    k_node<8, false><<<dim3(192), dim3(256), 0, stream>>>(
        feat2, s2b, n2b, einfo, A, bn1, out, F + 128, nullptr, nullptr);
}